// Round 12
// baseline (10484.139 us; speedup 1.0000x reference)
//
#include <hip/hip_runtime.h>
#include <hip/hip_fp16.h>

#define B_ 256
#define T_ 512
#define H_ 2048
#define C_ 128
#define ASTR 520        // LDS A row stride (fp16): 1040B ≡ 16 (mod 128) -> 2-way max (free, m136)
#define POLLCAP 50000   // bounded poll: deadlock -> fast absmax-fail, never a 600s timeout

// ws byte offsets (total 10 MB = r1-proven capacity)
#define WS_H0 (0u)
#define WS_H1 (1u << 20)
#define WS_BT (2u << 20)   // 8 MB fp16 BT[n=2048][s=2048] (W_hh^T, sigma-permuted K)

typedef _Float16 half8 __attribute__((ext_vector_type(8)));
typedef float floatx4 __attribute__((ext_vector_type(4)));

__device__ unsigned g_flags[1024];   // (rb*16+cb)*4 spacing; zeroed by init_h each call

// h storage K-permuted (r7-proven): within each 32-col block, storage 2j<-col j, 2j+1<-col j+16.
//   sigma(s)   = (s&~31) + ((s&31)>>1) + ((s&1)<<4)
//   sigma^-1(k)= (k&~31) | ((k&15)<<1) | ((k>>4)&1)

// IF$-coherent loads (sc0 sc1): read the device coherence point (r7-proven).
__device__ __forceinline__ half8 llc_load16(const _Float16* p) {
    union { unsigned long long u[2]; half8 h; } v;
    const unsigned long long* q = (const unsigned long long*)p;
    v.u[0] = __hip_atomic_load(q,     __ATOMIC_RELAXED, __HIP_MEMORY_SCOPE_AGENT);
    v.u[1] = __hip_atomic_load(q + 1, __ATOMIC_RELAXED, __HIP_MEMORY_SCOPE_AGENT);
    return v.h;
}

// ---- one-time: BT[n][s] = (fp16) W_hh[sigma(s)][n]  (read-only weights; L2-cacheable) ----
__global__ void convert_whh(const float* __restrict__ W, _Float16* __restrict__ BT) {
    __shared__ float tile[64][65];
    const int kb = blockIdx.x * 64, nb = blockIdx.y * 64;
    const int tid = threadIdx.x;
    const int rc = tid & 63, rr = tid >> 6;
#pragma unroll
    for (int i = 0; i < 16; ++i)
        tile[i * 4 + rr][rc] = W[(size_t)(kb + i * 4 + rr) * H_ + nb + rc];  // coalesced
    __syncthreads();
    const int j = tid & 15, blk = (tid >> 4) & 1, nof = tid >> 5;   // nof 0..7
#pragma unroll
    for (int i = 0; i < 8; ++i) {
        int n = i * 8 + nof;
        _Float16 v0 = (_Float16)tile[blk * 32 + j][n];        // orig col j   -> s even
        _Float16 v1 = (_Float16)tile[blk * 32 + 16 + j][n];   // orig col j+16-> s odd
        unsigned pk = ((unsigned)__builtin_bit_cast(unsigned short, v1) << 16)
                    |  (unsigned)__builtin_bit_cast(unsigned short, v0);
        *(unsigned*)(BT + (size_t)(nb + n) * H_ + kb + blk * 32 + 2 * j) = pk;
    }
}

// ---- h0 (permuted) = tanh(W_hx[x[:,0]] + b_h); zero flags ----
__global__ void init_h(const int* __restrict__ x, const float* __restrict__ W_hx,
                       const float* __restrict__ b_h, char* __restrict__ ws) {
    int idx = blockIdx.x * blockDim.x + threadIdx.x;   // over B_*H_
    if (idx < 1024) g_flags[idx] = 0;
    _Float16* h0 = (_Float16*)(ws + WS_H0);
    int b = idx >> 11, s = idx & (H_ - 1);
    int j = (s & ~31) + ((s & 31) >> 1) + ((s & 1) << 4);
    int xv = x[b * T_];
    h0[idx] = (_Float16)tanhf(W_hx[(size_t)xv * H_ + j] + b_h[j]);
}

// poll the 4 producers of chunk qq (col-blocks 4qq..4qq+3) for step t-1
#define POLL(qq) {                                                          \
    int guard = 0;                                                          \
    for (;;) {                                                              \
        unsigned fvv = need;                                                \
        if (l < 4) fvv = __hip_atomic_load(&g_flags[(rb * 16 + (qq) * 4 + l) * 4], \
                                           __ATOMIC_RELAXED, __HIP_MEMORY_SCOPE_AGENT); \
        if (__ballot(fvv >= need) == ~0ull) break;                          \
        if (++guard > POLLCAP) break;                                       \
        __builtin_amdgcn_s_sleep(2);                                        \
    } }

#define STAGE_LOAD(hb, qq, r) {                                             \
    const _Float16* sp = (hb) + (size_t)(rbr + srow) * H_ + (qq) * 512 + skb; \
    r[0] = llc_load16(sp);      r[1] = llc_load16(sp + 8);                  \
    r[2] = llc_load16(sp + 16); r[3] = llc_load16(sp + 24); }

#define STAGE_WRITE(buf, r) {                                               \
    _Float16* dp = &As[buf][srow][skb];                                     \
    *(half8*)(dp)      = r[0]; *(half8*)(dp + 8)  = r[1];                   \
    *(half8*)(dp + 16) = r[2]; *(half8*)(dp + 24) = r[3]; }

#define COMPUTE(qq) {                                                       \
    const _Float16* ar  = &As[(qq) & 1][l15][kl];                           \
    const _Float16* b0p = BT + (size_t)(cw + l15) * H_ + (qq) * 512 + kl;   \
    const _Float16* b1p = BT + (size_t)(cw + 16 + l15) * H_ + (qq) * 512 + kl; \
    _Pragma("unroll")                                                       \
    for (int i = 0; i < 16; ++i) {                                          \
        half8 a  = *(const half8*)(ar  + i * 32);                           \
        half8 b0 = *(const half8*)(b0p + i * 32);                           \
        half8 b1 = *(const half8*)(b1p + i * 32);                           \
        acc0 = __builtin_amdgcn_mfma_f32_16x16x32_f16(a, b0, acc0, 0, 0, 0);\
        acc1 = __builtin_amdgcn_mfma_f32_16x16x32_f16(a, b1, acc1, 0, 0, 0);\
    } }

// ---- recurrence: 256 WGs (1/CU) x 256 thr; WG tile 16(M) x 128(N) ----
// A (h rows) staged via LDS once per WG per step (IF$ traffic 64->16 MB/step);
// B streamed from read-only fp16 BT (normal cached loads; XCD=cb&7 -> 1MB slice L2-resident).
// Chunk-grain dataflow: storage chunk q's producers are col-blocks 4q..4q+3 (sigma is
// within-32-block). Publish/flag machinery = r7/r11-proven (cohort 64 -> 16 WGs).
__global__ __launch_bounds__(256, 1)
void rnn_steps(char* __restrict__ ws, const int* __restrict__ x,
               const float* __restrict__ W_hx, const float* __restrict__ b_h) {
    __shared__ _Float16 As[2][16][ASTR];   // 33.3 KB
    _Float16* h0 = (_Float16*)(ws + WS_H0);
    _Float16* h1 = (_Float16*)(ws + WS_H1);
    const _Float16* BT = (const _Float16*)(ws + WS_BT);

    const int bid = blockIdx.x;
    const int rb  = bid >> 4;          // rowblock 0..15 (16 batch rows)
    const int cb  = bid & 15;          // colblock 0..15 (128 cols); XCD = bid&7 = cb&7
    const int nb  = cb * 128;
    const int tid = threadIdx.x;
    const int w   = tid >> 6;
    const int l   = tid & 63;
    const int l15 = l & 15;
    const int q4  = l >> 4;
    const int kl  = q4 << 3;
    const int cw  = nb + w * 32;       // wave's 32-col block
    const int rbr = rb * 16;
    const int srow = tid >> 4;         // staging: row 0..15
    const int skb  = (tid & 15) * 32;  // staging: 32 fp16 per thread
    const int r0 = rbr + q4 * 4;
    const int c0 = cw + l15;
    const float bh0 = b_h[c0], bh1 = b_h[c0 + 16];
    unsigned* myflag = &g_flags[(rb * 16 + cb) * 4];

    for (int t = 1; t < T_; ++t) {
        const _Float16* __restrict__ hc = (t & 1) ? h0 : h1;  // h(t-1)
        _Float16* __restrict__ hn       = (t & 1) ? h1 : h0;  // h(t)
        const unsigned need = (unsigned)(t - 1);

        // epilogue-gather prefetch (warm L1/L2)
        int   xv[4];
        float wx0[4], wx1[4];
#pragma unroll
        for (int jj = 0; jj < 4; ++jj) xv[jj] = x[(r0 + jj) * T_ + t];
#pragma unroll
        for (int jj = 0; jj < 4; ++jj) {
            wx0[jj] = W_hx[(size_t)xv[jj] * H_ + c0];
            wx1[jj] = W_hx[(size_t)xv[jj] * H_ + c0 + 16];
        }

        floatx4 acc0 = {0.f, 0.f, 0.f, 0.f}, acc1 = {0.f, 0.f, 0.f, 0.f};

        // prologue: poll + stage chunk 0
        POLL(0);
        {
            half8 rA[4];
            STAGE_LOAD(hc, 0, rA);
            STAGE_WRITE(0, rA);
        }
        __syncthreads();

#pragma unroll
        for (int q = 0; q < 4; ++q) {
            half8 rN[4];
            if (q < 3) {
                POLL(q + 1);
                STAGE_LOAD(hc, q + 1, rN);   // IF$ latency hides under COMPUTE(q)
            }
            COMPUTE(q);
            if (q < 3) {
                __syncthreads();             // readers of As[(q+1)&1] (chunk q-1) done
                STAGE_WRITE((q + 1) & 1, rN);
                __syncthreads();
            }
        }

        // publish h(t): packed u32 atomic swaps at the IF$ (r7-proven), batched drain
        unsigned o[4];
#pragma unroll
        for (int jj = 0; jj < 4; ++jj) {
            float z0 = acc0[jj] + wx0[jj] + bh0;
            float z1 = acc1[jj] + wx1[jj] + bh1;
            _Float16 p0 = (_Float16)tanhf(z0), p1 = (_Float16)tanhf(z1);
            unsigned pv = ((unsigned)__builtin_bit_cast(unsigned short, p1) << 16)
                        |  (unsigned)__builtin_bit_cast(unsigned short, p0);
            unsigned* dstp = (unsigned*)(hn + (size_t)(r0 + jj) * H_ + cw + 2 * l15);
            o[jj] = __hip_atomic_exchange(dstp, pv, __ATOMIC_RELAXED,
                                          __HIP_MEMORY_SCOPE_AGENT);
        }
        asm volatile("" :: "v"(o[0]), "v"(o[1]), "v"(o[2]), "v"(o[3]));

        __syncthreads();                     // vmcnt drain: all swaps executed at IF$
        if (tid == 0) {
            __builtin_amdgcn_fence(__ATOMIC_RELEASE, "workgroup");   // ordering only
            __hip_atomic_fetch_add(myflag, 1u, __ATOMIC_RELAXED, __HIP_MEMORY_SCOPE_AGENT);
        }
        // no wait — next step's chunk polls gate on data readiness
    }
}

// ---- out[b,c] = h[b,:] @ W_ph + b_p (fp32); h in permuted storage order ----
__global__ void final_proj(const char* __restrict__ ws, const float* __restrict__ W_ph,
                           const float* __restrict__ b_p, float* __restrict__ out) {
    __shared__ float part[C_];
    const _Float16* h = (const _Float16*)(ws + WS_H1);   // h after t=511 (odd)
    const int b  = blockIdx.x;
    const int c  = threadIdx.x & (C_ - 1);
    const int hh = threadIdx.x >> 7;
    const int j0 = hh * (H_ / 2);
    float acc = 0.f;
#pragma unroll 4
    for (int s = j0; s < j0 + H_ / 2; ++s) {
        int k = (s & ~31) + ((s & 31) >> 1) + ((s & 1) << 4);   // sigma(s)
        acc = fmaf((float)h[(size_t)b * H_ + s], W_ph[k * C_ + c], acc);
    }
    if (hh) part[c] = acc;
    __syncthreads();
    if (!hh) out[b * C_ + c] = acc + part[c] + b_p[c];
}

extern "C" void kernel_launch(void* const* d_in, const int* in_sizes, int n_in,
                              void* d_out, int out_size, void* d_ws, size_t ws_size,
                              hipStream_t stream) {
    const int*   x    = (const int*)d_in[0];
    const float* W_hx = (const float*)d_in[1];
    const float* W_hh = (const float*)d_in[2];
    const float* W_ph = (const float*)d_in[3];
    const float* b_h  = (const float*)d_in[4];
    const float* b_p  = (const float*)d_in[5];
    float* out = (float*)d_out;
    char* ws = (char*)d_ws;

    convert_whh<<<dim3(H_ / 64, H_ / 64), 256, 0, stream>>>(W_hh, (_Float16*)(ws + WS_BT));
    init_h<<<(B_ * H_) / 256, 256, 0, stream>>>(x, W_hx, b_h, ws);

    char* pws = ws;
    const int* px = x; const float* pwhx = W_hx; const float* pbh = b_h;
    void* args[] = {(void*)&pws, (void*)&px, (void*)&pwhx, (void*)&pbh};
    hipError_t e = hipLaunchCooperativeKernel((void*)rnn_steps, dim3(256), dim3(256),
                                              args, 0, stream);
    if (e != hipSuccess) {
        rnn_steps<<<dim3(256), dim3(256), 0, stream>>>(pws, px, pwhx, pbh);
    }

    final_proj<<<B_, 256, 0, stream>>>(ws, W_ph, b_p, out);
}